// Round 4
// baseline (655.766 us; speedup 1.0000x reference)
//
#include <hip/hip_runtime.h>
#include <math.h>

// feat_1: (16,32,256,256) f32; feat_2: (16,32,64,64) f32; xcorr/out: (16,32,319,319) f32
#define H1 256
#define W1 256
#define HO 319
#define WO 319
#define SEG 8            // row segments per channel; one WAVE per (channel, segment)
#define ROWS_PER 40      // 319/8 rounded up

__device__ __forceinline__ float up0(float x, int d, int lane) {
  float s = __shfl_up(x, (unsigned)d, 64);
  return (lane >= d) ? s : 0.0f;
}
__device__ __forceinline__ float dn0(float x, int d, int lane) {
  float s = __shfl_down(x, (unsigned)d, 64);
  return (lane + d <= 63) ? s : 0.0f;
}

// Given this lane's 4 column values a0..a3 (cols 4*lane .. 4*lane+3, all >= 0),
// produce the 64-wide windowed sums:
//   wi[j]: window ending at xo = 4*lane+j        (interior, clipped at 0)
//   wt[j]: window ending at xo = 256+4*lane+j    (tail, clipped at 255)
__device__ __forceinline__ void win7(float a0, float a1, float a2, float a3,
                                     int lane, float wi[4], float wt[4]) {
  float L0 = a0, L1 = L0 + a1, L2 = L1 + a2, L3 = L2 + a3;  // in-thread prefixes
  float sf2 = a3, sf1 = sf2 + a2, sf0 = sf1 + a1;           // in-thread suffixes (slots > j)
  float b1 = L3 + up0(L3, 1, lane);   // 2-window incl
  float b2 = b1 + up0(b1, 2, lane);   // 4-window incl
  float b3 = b2 + up0(b2, 4, lane);   // 8-window incl
  float M = up0(b3, 1, lane) + up0(b2, 9, lane) + up0(b1, 13, lane) + up0(L3, 15, lane);
  float c1 = L3 + dn0(L3, 1, lane);
  float c2 = c1 + dn0(c1, 2, lane);
  float c3 = c2 + dn0(c2, 4, lane);
  float c4 = c3 + dn0(c3, 8, lane);
  float T49 = dn0(c4, 49, lane);      // sum of totals over lanes [lane+49, 63]
  float g0 = up0(sf0, 16, lane), g1 = up0(sf1, 16, lane), g2 = up0(sf2, 16, lane);
  float h0 = dn0(sf0, 48, lane), h1 = dn0(sf1, 48, lane), h2 = dn0(sf2, 48, lane);
  wi[0] = g0 + M + L0;  wi[1] = g1 + M + L1;  wi[2] = g2 + M + L2;  wi[3] = M + L3;
  wt[0] = h0 + T49;     wt[1] = h1 + T49;     wt[2] = h2 + T49;     wt[3] = T49;
}

__device__ __forceinline__ float out_val(float ws, float ws2, float xc,
                                         float mean, float ssd) {
  const float FLOOR_  = 1.1920928955078125e-07f;  // float32 eps
  const float FLOOR2_ = FLOOR_ * FLOOR_;
  float num  = xc - ws * mean;
  float w2c  = ws2 - ws * ws * (1.0f / 4096.0f);
  float t    = fmaxf(w2c * ssd, 0.0f);            // denom^2
  float numc = fmaxf(num, FLOOR_);
  return (t > FLOOR2_) ? (numc * __frsqrt_rn(t)) : 0.0f;
}

__global__ __launch_bounds__(256, 4)
void ncc_norm_kernel(const float* __restrict__ feat1,
                     const float* __restrict__ feat2,
                     const float* __restrict__ xcorr,
                     float* __restrict__ out) {
  const int tid  = threadIdx.x;
  const int lane = tid & 63;
  const int wv   = tid >> 6;

  // XCD-chunked bijective swizzle for grid=1024 (= 8 XCD * 128):
  // a channel's 2 blocks (8 segments) are adjacent in dispatch order on one XCD.
  const int d   = blockIdx.x;          // 0..1023
  const int xcd = d & 7;
  const int i   = d >> 3;              // 0..127
  const int bc  = xcd * 64 + (i >> 1); // 0..511 channel
  const int seg = (i & 1) * 4 + wv;    // 0..7 row segment

  const float* f1 = feat1 + (size_t)bc * (H1 * W1);
  const float* f2 = feat2 + (size_t)bc * 4096;

  // ---- per-wave feat_2 stats ----
  float sum = 0.0f, sumsq = 0.0f;
  #pragma unroll
  for (int r = 0; r < 16; ++r) {
    float4 qq = *(const float4*)(f2 + r * 256 + 4 * lane);
    sum   += (qq.x + qq.y) + (qq.z + qq.w);
    sumsq += (qq.x * qq.x + qq.y * qq.y) + (qq.z * qq.z + qq.w * qq.w);
  }
  #pragma unroll
  for (int dd = 1; dd < 64; dd <<= 1) {
    sum   += __shfl_xor(sum,   dd, 64);
    sumsq += __shfl_xor(sumsq, dd, 64);
  }
  float mean = sum * (1.0f / 4096.0f);
  float ssd  = sumsq - sum * mean;

  const int y0 = seg * ROWS_PER;
  const int y1 = min(HO, y0 + ROWS_PER);
  const int x4 = 4 * lane;

  // ---- vertical running window sums (fp64; exact) ----
  double v0 = 0, v1 = 0, v2 = 0, v3 = 0;
  double q0 = 0, q1 = 0, q2 = 0, q3 = 0;
  for (int r = max(0, y0 - 64); r < min(y0, H1); ++r) {
    float4 t = *(const float4*)(f1 + r * W1 + x4);
    v0 += t.x; q0 += (double)t.x * t.x;
    v1 += t.y; q1 += (double)t.y * t.y;
    v2 += t.z; q2 += (double)t.z * t.z;
    v3 += t.w; q3 += (double)t.w * t.w;
  }

#define LOADF(row) (*(const float4*)(f1 + (row) * W1 + x4))

// xcorr row loader: interior (all lanes) + tail (lanes 0..15); unloaded slots = 0
#define LOADX(row, xi, xt) do {                                          \
    const float* xr_ = xcorr + (size_t)(bc * HO + (row)) * WO;           \
    xi[0] = xr_[x4 + 0]; xi[1] = xr_[x4 + 1];                            \
    xi[2] = xr_[x4 + 2]; xi[3] = xr_[x4 + 3];                            \
    xt[0] = 0.0f; xt[1] = 0.0f; xt[2] = 0.0f; xt[3] = 0.0f;              \
    if (lane < 16) {                                                     \
      xt[0] = xr_[256 + x4 + 0];                                         \
      xt[1] = xr_[256 + x4 + 1];                                         \
      xt[2] = xr_[256 + x4 + 2];                                         \
      if (lane < 15) xt[3] = xr_[256 + x4 + 3];                          \
    }                                                                    \
  } while (0)

  // feat_1 pair-prefetch registers (entering A/B = rows y,y+1; leaving A/B)
  float4 eA, eB, lA, lB;
  {
    int yn = y0;
    if (yn < H1)                        eA = LOADF(yn);
    if (yn + 1 < H1 && yn + 1 < y1)     eB = LOADF(yn + 1);
    if (yn >= 64)                       lA = LOADF(yn - 64);
    if (yn + 1 >= 64 && yn + 1 < y1)    lB = LOADF(yn - 63);
  }

  // xcorr double-buffer: preload pair 0 (every segment has >= 2 rows)
  float xiA[4], xtA[4], xiB[4], xtB[4];
  LOADX(y0, xiA, xtA);
  LOADX(y0 + 1, xiB, xtB);

  int y = y0;
  for (; y + 1 < y1; y += 2) {
    // ---- issue NEXT pair's xcorr loads first (consumed next iteration) ----
    float nxiA[4], nxtA[4], nxiB[4], nxtB[4];
    const bool hasA = (y + 2 < y1);
    const bool hasB = (y + 3 < y1);
    if (hasA) LOADX(y + 2, nxiA, nxtA);
    if (hasB) LOADX(y + 3, nxiB, nxtB);

    // ---- row y: consume prefetched feat_1 rows, snapshot ----
    if (y < H1) {
      v0 += eA.x; q0 += (double)eA.x * eA.x;
      v1 += eA.y; q1 += (double)eA.y * eA.y;
      v2 += eA.z; q2 += (double)eA.z * eA.z;
      v3 += eA.w; q3 += (double)eA.w * eA.w;
    }
    if (y >= 64) {
      v0 -= lA.x; q0 -= (double)lA.x * lA.x;
      v1 -= lA.y; q1 -= (double)lA.y * lA.y;
      v2 -= lA.z; q2 -= (double)lA.z * lA.z;
      v3 -= lA.w; q3 -= (double)lA.w * lA.w;
    }
    float wA0 = (float)v0, wA1 = (float)v1, wA2 = (float)v2, wA3 = (float)v3;
    float uA0 = (float)q0, uA1 = (float)q1, uA2 = (float)q2, uA3 = (float)q3;

    // ---- row y+1: consume, snapshot ----
    if (y + 1 < H1) {
      v0 += eB.x; q0 += (double)eB.x * eB.x;
      v1 += eB.y; q1 += (double)eB.y * eB.y;
      v2 += eB.z; q2 += (double)eB.z * eB.z;
      v3 += eB.w; q3 += (double)eB.w * eB.w;
    }
    if (y + 1 >= 64) {
      v0 -= lB.x; q0 -= (double)lB.x * lB.x;
      v1 -= lB.y; q1 -= (double)lB.y * lB.y;
      v2 -= lB.z; q2 -= (double)lB.z * lB.z;
      v3 -= lB.w; q3 -= (double)lB.w * lB.w;
    }
    float wB0 = (float)v0, wB1 = (float)v1, wB2 = (float)v2, wB3 = (float)v3;
    float uB0 = (float)q0, uB1 = (float)q1, uB2 = (float)q2, uB3 = (float)q3;

    // ---- prefetch feat_1 rows for next pair ----
    {
      int yn = y + 2;
      if (yn < y1) {
        if (yn < H1)                     eA = LOADF(yn);
        if (yn + 1 < H1 && yn + 1 < y1)  eB = LOADF(yn + 1);
        if (yn >= 64)                    lA = LOADF(yn - 64);
        if (yn + 1 >= 64 && yn + 1 < y1) lB = LOADF(yn - 63);
      }
    }

    // ---- 4 independent shuffle chains (ILP across rows & quantities) ----
    float wsIA[4], wsTA[4], sqIA[4], sqTA[4];
    float wsIB[4], wsTB[4], sqIB[4], sqTB[4];
    win7(wA0, wA1, wA2, wA3, lane, wsIA, wsTA);
    win7(uA0, uA1, uA2, uA3, lane, sqIA, sqTA);
    win7(wB0, wB1, wB2, wB3, lane, wsIB, wsTB);
    win7(uB0, uB1, uB2, uB3, lane, sqIB, sqTB);

    const int rbA = (bc * HO + y) * WO;
    float* oA = out + rbA;
    float* oB = out + rbA + WO;
    #pragma unroll
    for (int j = 0; j < 4; ++j) {
      oA[x4 + j] = out_val(wsIA[j], sqIA[j], xiA[j], mean, ssd);
      oB[x4 + j] = out_val(wsIB[j], sqIB[j], xiB[j], mean, ssd);
    }
    if (lane < 16) {
      oA[256 + x4 + 0] = out_val(wsTA[0], sqTA[0], xtA[0], mean, ssd);
      oB[256 + x4 + 0] = out_val(wsTB[0], sqTB[0], xtB[0], mean, ssd);
      oA[256 + x4 + 1] = out_val(wsTA[1], sqTA[1], xtA[1], mean, ssd);
      oB[256 + x4 + 1] = out_val(wsTB[1], sqTB[1], xtB[1], mean, ssd);
      oA[256 + x4 + 2] = out_val(wsTA[2], sqTA[2], xtA[2], mean, ssd);
      oB[256 + x4 + 2] = out_val(wsTB[2], sqTB[2], xtB[2], mean, ssd);
      if (lane < 15) {
        oA[256 + x4 + 3] = out_val(wsTA[3], sqTA[3], xtA[3], mean, ssd);
        oB[256 + x4 + 3] = out_val(wsTB[3], sqTB[3], xtB[3], mean, ssd);
      }
    }

    // ---- rotate xcorr double-buffer ----
    #pragma unroll
    for (int j = 0; j < 4; ++j) {
      if (hasA) { xiA[j] = nxiA[j]; xtA[j] = nxtA[j]; }
      if (hasB) { xiB[j] = nxiB[j]; xtB[j] = nxtB[j]; }
    }
  }

  // ---- odd tail row (only segments with 39 rows) — xcorr already in A-buffer ----
  if (y < y1) {
    if (y < H1) {
      v0 += eA.x; q0 += (double)eA.x * eA.x;
      v1 += eA.y; q1 += (double)eA.y * eA.y;
      v2 += eA.z; q2 += (double)eA.z * eA.z;
      v3 += eA.w; q3 += (double)eA.w * eA.w;
    }
    if (y >= 64) {
      v0 -= lA.x; q0 -= (double)lA.x * lA.x;
      v1 -= lA.y; q1 -= (double)lA.y * lA.y;
      v2 -= lA.z; q2 -= (double)lA.z * lA.z;
      v3 -= lA.w; q3 -= (double)lA.w * lA.w;
    }
    float w0 = (float)v0, w1 = (float)v1, w2 = (float)v2, w3 = (float)v3;
    float u0 = (float)q0, u1 = (float)q1, u2 = (float)q2, u3 = (float)q3;

    float wsI[4], wsT[4], sqI[4], sqT[4];
    win7(w0, w1, w2, w3, lane, wsI, wsT);
    win7(u0, u1, u2, u3, lane, sqI, sqT);

    const int rowbase = (bc * HO + y) * WO;
    float* orw = out + rowbase;
    #pragma unroll
    for (int j = 0; j < 4; ++j)
      orw[x4 + j] = out_val(wsI[j], sqI[j], xiA[j], mean, ssd);
    if (lane < 16) {
      orw[256 + x4 + 0] = out_val(wsT[0], sqT[0], xtA[0], mean, ssd);
      orw[256 + x4 + 1] = out_val(wsT[1], sqT[1], xtA[1], mean, ssd);
      orw[256 + x4 + 2] = out_val(wsT[2], sqT[2], xtA[2], mean, ssd);
      if (lane < 15)
        orw[256 + x4 + 3] = out_val(wsT[3], sqT[3], xtA[3], mean, ssd);
    }
  }
#undef LOADF
#undef LOADX
}

extern "C" void kernel_launch(void* const* d_in, const int* in_sizes, int n_in,
                              void* d_out, int out_size, void* d_ws, size_t ws_size,
                              hipStream_t stream) {
  const float* feat1 = (const float*)d_in[0];
  const float* feat2 = (const float*)d_in[1];
  const float* xcorr = (const float*)d_in[2];
  float* out = (float*)d_out;

  dim3 grid(512 * SEG / 4);   // 1024 blocks, 4 waves/block, one wave per (channel, segment)
  ncc_norm_kernel<<<grid, 256, 0, stream>>>(feat1, feat2, xcorr, out);
}

// Round 5
// 509.887 us; speedup vs baseline: 1.2861x; 1.2861x over previous
//
#include <hip/hip_runtime.h>
#include <math.h>

// feat_1: (16,32,256,256) f32; feat_2: (16,32,64,64) f32; xcorr/out: (16,32,319,319) f32
#define H1 256
#define W1 256
#define HO 319
#define WO 319
#define SEG 8            // row segments per channel; one WAVE per (channel, segment)
#define ROWS_PER 40      // 319/8 rounded up

// ---- unaligned (4B-aligned) 16-byte global accesses ----
// gfx950 global_load/store_dwordx4 require only dword alignment; rows are
// 319 floats so 16B alignment is impossible -- memcpy lowers to dwordx4.
struct f4u { float x, y, z, w; };
__device__ __forceinline__ f4u load4u(const float* p) {
  f4u r; __builtin_memcpy(&r, p, 16); return r;
}
__device__ __forceinline__ void store4u(float* p, const f4u& v) {
  __builtin_memcpy(p, &v, 16);
}

__device__ __forceinline__ float up0(float x, int d, int lane) {
  float s = __shfl_up(x, (unsigned)d, 64);
  return (lane >= d) ? s : 0.0f;
}
__device__ __forceinline__ float dn0(float x, int d, int lane) {
  float s = __shfl_down(x, (unsigned)d, 64);
  return (lane + d <= 63) ? s : 0.0f;
}

// Given this lane's 4 column values a0..a3 (cols 4*lane .. 4*lane+3, all >= 0),
// produce the 64-wide windowed sums:
//   wi[j]: window ending at xo = 4*lane+j        (interior, clipped at 0)
//   wt[j]: window ending at xo = 256+4*lane+j    (tail, clipped at 255)
__device__ __forceinline__ void win7(float a0, float a1, float a2, float a3,
                                     int lane, float wi[4], float wt[4]) {
  float L0 = a0, L1 = L0 + a1, L2 = L1 + a2, L3 = L2 + a3;  // in-thread prefixes
  float sf2 = a3, sf1 = sf2 + a2, sf0 = sf1 + a1;           // in-thread suffixes (slots > j)
  float b1 = L3 + up0(L3, 1, lane);   // 2-window incl
  float b2 = b1 + up0(b1, 2, lane);   // 4-window incl
  float b3 = b2 + up0(b2, 4, lane);   // 8-window incl
  float M = up0(b3, 1, lane) + up0(b2, 9, lane) + up0(b1, 13, lane) + up0(L3, 15, lane);
  float c1 = L3 + dn0(L3, 1, lane);
  float c2 = c1 + dn0(c1, 2, lane);
  float c3 = c2 + dn0(c2, 4, lane);
  float c4 = c3 + dn0(c3, 8, lane);
  float T49 = dn0(c4, 49, lane);      // sum of totals over lanes [lane+49, 63]
  float g0 = up0(sf0, 16, lane), g1 = up0(sf1, 16, lane), g2 = up0(sf2, 16, lane);
  float h0 = dn0(sf0, 48, lane), h1 = dn0(sf1, 48, lane), h2 = dn0(sf2, 48, lane);
  wi[0] = g0 + M + L0;  wi[1] = g1 + M + L1;  wi[2] = g2 + M + L2;  wi[3] = M + L3;
  wt[0] = h0 + T49;     wt[1] = h1 + T49;     wt[2] = h2 + T49;     wt[3] = T49;
}

__device__ __forceinline__ float out_val(float ws, float ws2, float xc,
                                         float mean, float ssd) {
  const float FLOOR_  = 1.1920928955078125e-07f;  // float32 eps
  const float FLOOR2_ = FLOOR_ * FLOOR_;
  float num  = xc - ws * mean;
  float w2c  = ws2 - ws * ws * (1.0f / 4096.0f);
  float t    = fmaxf(w2c * ssd, 0.0f);            // denom^2
  float numc = fmaxf(num, FLOOR_);
  return (t > FLOOR2_) ? (numc * __frsqrt_rn(t)) : 0.0f;
}

__global__ __launch_bounds__(256, 4)
void ncc_norm_kernel(const float* __restrict__ feat1,
                     const float* __restrict__ feat2,
                     const float* __restrict__ xcorr,
                     float* __restrict__ out) {
  const int tid  = threadIdx.x;
  const int lane = tid & 63;
  const int wv   = tid >> 6;

  // XCD-chunked bijective swizzle for grid=1024 (= 8 XCD * 128):
  // a channel's 2 blocks (8 segments) are adjacent in dispatch order on one XCD.
  const int d   = blockIdx.x;          // 0..1023
  const int xcd = d & 7;
  const int i   = d >> 3;              // 0..127
  const int bc  = xcd * 64 + (i >> 1); // 0..511 channel
  const int seg = (i & 1) * 4 + wv;    // 0..7 row segment

  const float* f1 = feat1 + (size_t)bc * (H1 * W1);
  const float* f2 = feat2 + (size_t)bc * 4096;

  // ---- per-wave feat_2 stats ----
  float sum = 0.0f, sumsq = 0.0f;
  #pragma unroll
  for (int r = 0; r < 16; ++r) {
    float4 qq = *(const float4*)(f2 + r * 256 + 4 * lane);
    sum   += (qq.x + qq.y) + (qq.z + qq.w);
    sumsq += (qq.x * qq.x + qq.y * qq.y) + (qq.z * qq.z + qq.w * qq.w);
  }
  #pragma unroll
  for (int dd = 1; dd < 64; dd <<= 1) {
    sum   += __shfl_xor(sum,   dd, 64);
    sumsq += __shfl_xor(sumsq, dd, 64);
  }
  float mean = sum * (1.0f / 4096.0f);
  float ssd  = sumsq - sum * mean;

  const int y0 = seg * ROWS_PER;
  const int y1 = min(HO, y0 + ROWS_PER);
  const int x4 = 4 * lane;

  // ---- vertical running window sums (fp64; exact) ----
  double v0 = 0, v1 = 0, v2 = 0, v3 = 0;
  double q0 = 0, q1 = 0, q2 = 0, q3 = 0;
  for (int r = max(0, y0 - 64); r < min(y0, H1); ++r) {
    float4 t = *(const float4*)(f1 + r * W1 + x4);
    v0 += t.x; q0 += (double)t.x * t.x;
    v1 += t.y; q1 += (double)t.y * t.y;
    v2 += t.z; q2 += (double)t.z * t.z;
    v3 += t.w; q3 += (double)t.w * t.w;
  }

#define LOADF(row) (*(const float4*)(f1 + (row) * W1 + x4))

  // feat_1 pair-prefetch registers (entering A/B = rows y,y+1; leaving A/B)
  float4 eA, eB, lA, lB;
  {
    int yn = y0;
    if (yn < H1)                        eA = LOADF(yn);
    if (yn + 1 < H1 && yn + 1 < y1)     eB = LOADF(yn + 1);
    if (yn >= 64)                       lA = LOADF(yn - 64);
    if (yn + 1 >= 64 && yn + 1 < y1)    lB = LOADF(yn - 63);
  }

  int y = y0;
  for (; y + 1 < y1; y += 2) {
    const int rbA = (bc * HO + y) * WO;
    const int rbB = rbA + WO;
    const float* xrA = xcorr + rbA;
    const float* xrB = xcorr + rbB;

    // issue both rows' xcorr loads up front (consumed after 4x win7)
    // interior: one 16B load per lane; tail: lanes 0..14 16B, lane 15 3 scalars
    f4u xiA = load4u(xrA + x4);
    f4u xiB = load4u(xrB + x4);
    f4u xtA = {0,0,0,0}, xtB = {0,0,0,0};
    if (lane < 15) {
      xtA = load4u(xrA + 256 + x4);
      xtB = load4u(xrB + 256 + x4);
    } else if (lane == 15) {
      xtA.x = xrA[316]; xtA.y = xrA[317]; xtA.z = xrA[318];
      xtB.x = xrB[316]; xtB.y = xrB[317]; xtB.z = xrB[318];
    }

    // ---- row y: consume prefetched feat_1 rows, snapshot ----
    if (y < H1) {
      v0 += eA.x; q0 += (double)eA.x * eA.x;
      v1 += eA.y; q1 += (double)eA.y * eA.y;
      v2 += eA.z; q2 += (double)eA.z * eA.z;
      v3 += eA.w; q3 += (double)eA.w * eA.w;
    }
    if (y >= 64) {
      v0 -= lA.x; q0 -= (double)lA.x * lA.x;
      v1 -= lA.y; q1 -= (double)lA.y * lA.y;
      v2 -= lA.z; q2 -= (double)lA.z * lA.z;
      v3 -= lA.w; q3 -= (double)lA.w * lA.w;
    }
    float wA0 = (float)v0, wA1 = (float)v1, wA2 = (float)v2, wA3 = (float)v3;
    float uA0 = (float)q0, uA1 = (float)q1, uA2 = (float)q2, uA3 = (float)q3;

    // ---- row y+1: consume, snapshot ----
    if (y + 1 < H1) {
      v0 += eB.x; q0 += (double)eB.x * eB.x;
      v1 += eB.y; q1 += (double)eB.y * eB.y;
      v2 += eB.z; q2 += (double)eB.z * eB.z;
      v3 += eB.w; q3 += (double)eB.w * eB.w;
    }
    if (y + 1 >= 64) {
      v0 -= lB.x; q0 -= (double)lB.x * lB.x;
      v1 -= lB.y; q1 -= (double)lB.y * lB.y;
      v2 -= lB.z; q2 -= (double)lB.z * lB.z;
      v3 -= lB.w; q3 -= (double)lB.w * lB.w;
    }
    float wB0 = (float)v0, wB1 = (float)v1, wB2 = (float)v2, wB3 = (float)v3;
    float uB0 = (float)q0, uB1 = (float)q1, uB2 = (float)q2, uB3 = (float)q3;

    // ---- prefetch feat_1 rows for next pair (hide L2/L3/HBM latency) ----
    {
      int yn = y + 2;
      if (yn < y1) {
        if (yn < H1)                     eA = LOADF(yn);
        if (yn + 1 < H1 && yn + 1 < y1)  eB = LOADF(yn + 1);
        if (yn >= 64)                    lA = LOADF(yn - 64);
        if (yn + 1 >= 64 && yn + 1 < y1) lB = LOADF(yn - 63);
      }
    }

    // ---- 4 independent shuffle chains (ILP across rows & quantities) ----
    float wsIA[4], wsTA[4], sqIA[4], sqTA[4];
    float wsIB[4], wsTB[4], sqIB[4], sqTB[4];
    win7(wA0, wA1, wA2, wA3, lane, wsIA, wsTA);
    win7(uA0, uA1, uA2, uA3, lane, sqIA, sqTA);
    win7(wB0, wB1, wB2, wB3, lane, wsIB, wsTB);
    win7(uB0, uB1, uB2, uB3, lane, sqIB, sqTB);

    float* oA = out + rbA;
    float* oB = out + rbB;
    {
      f4u sA, sB;
      sA.x = out_val(wsIA[0], sqIA[0], xiA.x, mean, ssd);
      sA.y = out_val(wsIA[1], sqIA[1], xiA.y, mean, ssd);
      sA.z = out_val(wsIA[2], sqIA[2], xiA.z, mean, ssd);
      sA.w = out_val(wsIA[3], sqIA[3], xiA.w, mean, ssd);
      sB.x = out_val(wsIB[0], sqIB[0], xiB.x, mean, ssd);
      sB.y = out_val(wsIB[1], sqIB[1], xiB.y, mean, ssd);
      sB.z = out_val(wsIB[2], sqIB[2], xiB.z, mean, ssd);
      sB.w = out_val(wsIB[3], sqIB[3], xiB.w, mean, ssd);
      store4u(oA + x4, sA);
      store4u(oB + x4, sB);
    }
    if (lane < 15) {
      f4u sA, sB;
      sA.x = out_val(wsTA[0], sqTA[0], xtA.x, mean, ssd);
      sA.y = out_val(wsTA[1], sqTA[1], xtA.y, mean, ssd);
      sA.z = out_val(wsTA[2], sqTA[2], xtA.z, mean, ssd);
      sA.w = out_val(wsTA[3], sqTA[3], xtA.w, mean, ssd);
      sB.x = out_val(wsTB[0], sqTB[0], xtB.x, mean, ssd);
      sB.y = out_val(wsTB[1], sqTB[1], xtB.y, mean, ssd);
      sB.z = out_val(wsTB[2], sqTB[2], xtB.z, mean, ssd);
      sB.w = out_val(wsTB[3], sqTB[3], xtB.w, mean, ssd);
      store4u(oA + 256 + x4, sA);
      store4u(oB + 256 + x4, sB);
    } else if (lane == 15) {
      oA[316] = out_val(wsTA[0], sqTA[0], xtA.x, mean, ssd);
      oA[317] = out_val(wsTA[1], sqTA[1], xtA.y, mean, ssd);
      oA[318] = out_val(wsTA[2], sqTA[2], xtA.z, mean, ssd);
      oB[316] = out_val(wsTB[0], sqTB[0], xtB.x, mean, ssd);
      oB[317] = out_val(wsTB[1], sqTB[1], xtB.y, mean, ssd);
      oB[318] = out_val(wsTB[2], sqTB[2], xtB.z, mean, ssd);
    }
  }

  // ---- odd tail row (only segments with 39 rows) ----
  if (y < y1) {
    const int rowbase = (bc * HO + y) * WO;
    const float* xr = xcorr + rowbase;
    float* orw      = out   + rowbase;

    f4u xi = load4u(xr + x4);
    f4u xt = {0,0,0,0};
    if (lane < 15) {
      xt = load4u(xr + 256 + x4);
    } else if (lane == 15) {
      xt.x = xr[316]; xt.y = xr[317]; xt.z = xr[318];
    }

    if (y < H1) {
      v0 += eA.x; q0 += (double)eA.x * eA.x;
      v1 += eA.y; q1 += (double)eA.y * eA.y;
      v2 += eA.z; q2 += (double)eA.z * eA.z;
      v3 += eA.w; q3 += (double)eA.w * eA.w;
    }
    if (y >= 64) {
      v0 -= lA.x; q0 -= (double)lA.x * lA.x;
      v1 -= lA.y; q1 -= (double)lA.y * lA.y;
      v2 -= lA.z; q2 -= (double)lA.z * lA.z;
      v3 -= lA.w; q3 -= (double)lA.w * lA.w;
    }
    float w0 = (float)v0, w1 = (float)v1, w2 = (float)v2, w3 = (float)v3;
    float u0 = (float)q0, u1 = (float)q1, u2 = (float)q2, u3 = (float)q3;

    float wsI[4], wsT[4], sqI[4], sqT[4];
    win7(w0, w1, w2, w3, lane, wsI, wsT);
    win7(u0, u1, u2, u3, lane, sqI, sqT);

    {
      f4u s;
      s.x = out_val(wsI[0], sqI[0], xi.x, mean, ssd);
      s.y = out_val(wsI[1], sqI[1], xi.y, mean, ssd);
      s.z = out_val(wsI[2], sqI[2], xi.z, mean, ssd);
      s.w = out_val(wsI[3], sqI[3], xi.w, mean, ssd);
      store4u(orw + x4, s);
    }
    if (lane < 15) {
      f4u s;
      s.x = out_val(wsT[0], sqT[0], xt.x, mean, ssd);
      s.y = out_val(wsT[1], sqT[1], xt.y, mean, ssd);
      s.z = out_val(wsT[2], sqT[2], xt.z, mean, ssd);
      s.w = out_val(wsT[3], sqT[3], xt.w, mean, ssd);
      store4u(orw + 256 + x4, s);
    } else if (lane == 15) {
      orw[316] = out_val(wsT[0], sqT[0], xt.x, mean, ssd);
      orw[317] = out_val(wsT[1], sqT[1], xt.y, mean, ssd);
      orw[318] = out_val(wsT[2], sqT[2], xt.z, mean, ssd);
    }
  }
#undef LOADF
}

extern "C" void kernel_launch(void* const* d_in, const int* in_sizes, int n_in,
                              void* d_out, int out_size, void* d_ws, size_t ws_size,
                              hipStream_t stream) {
  const float* feat1 = (const float*)d_in[0];
  const float* feat2 = (const float*)d_in[1];
  const float* xcorr = (const float*)d_in[2];
  float* out = (float*)d_out;

  dim3 grid(512 * SEG / 4);   // 1024 blocks, 4 waves/block, one wave per (channel, segment)
  ncc_norm_kernel<<<grid, 256, 0, stream>>>(feat1, feat2, xcorr, out);
}